// Round 7
// baseline (9776.484 us; speedup 1.0000x reference)
//
#include <hip/hip_runtime.h>
#include <stdint.h>

// ScannedRNN: T=1024, B=128, D=512 GRU with resets + straight-through clip.
// prep (weight convert/pack) -> fused kernel: blocks 0-127 = persistent RNN
// (r5-proven tagged-word agent exchange, Wh in VGPRs), blocks 128-255 = input
// GEMM tile loop feeding gi via agent stores + per-t done counters. All 256
// blocks co-resident (<= 256 CUs) so no placement assumptions.

typedef float f32x4 __attribute__((ext_vector_type(4)));
typedef short s16x8 __attribute__((ext_vector_type(8)));

#define DD 512
#define BB 128
#define TT 1024
#define SM_BYTES 43008

static __device__ __forceinline__ unsigned short f2bf(float f) {
  uint32_t u = __builtin_bit_cast(uint32_t, f);
  u = (u + 0x7fffu + ((u >> 16) & 1u)) >> 16;   // RNE
  return (unsigned short)u;
}
static __device__ __forceinline__ float b2f(uint32_t bits) {
  return __builtin_bit_cast(float, bits << 16);
}
static __device__ __forceinline__ s16x8 ldsfrag(const char* p) {
  return __builtin_bit_cast(s16x8, *reinterpret_cast<const uint4*>(p));
}

// ---------------- prep: convert weights to bf16, packed layouts ----------------
__global__ void prep(const float* __restrict__ Wi, const float* __restrict__ Whrz,
                     const float* __restrict__ Whn,
                     unsigned short* __restrict__ WiT, unsigned short* __restrict__ Wpk) {
  int i = blockIdx.x * 256 + threadIdx.x;
  if (i < 786432) {
    int n = i >> 9, k = i & 511;
    WiT[i] = f2bf(Wi[(size_t)k * 1536 + n]);
  } else {
    int j = i - 786432;
    int ck = j >> 9;
    int k = j & 511;
    int cj = ck / 96, c96 = ck % 96;
    int g = c96 >> 5, cc = c96 & 31;
    float v = (g < 2) ? Whrz[(size_t)k * 1024 + g * 512 + cj * 32 + cc]
                      : Whn[(size_t)k * 512 + cj * 32 + cc];
    Wpk[j] = f2bf(v);
  }
}

// ---------------- tag0: mirror slot0 <- tagged(epoch 0) h0; f32 mirror <- h0 ----
__global__ void tag0(const float* __restrict__ h0, uint32_t* __restrict__ hxt,
                     float* __restrict__ hbF) {
  int i = blockIdx.x * 512 + threadIdx.x;   // 65536
  float v = h0[i];
  hxt[i] = (uint32_t)f2bf(v);               // tag 0
  hbF[i] = v;
}

// ---------------- resets dtype probe (bool bytes vs int32) ----------------
__global__ void scanR(const int* __restrict__ r, int* __restrict__ flag) {
  int i = blockIdx.x * 256 + threadIdx.x;       // 32768 ints = 131072 bytes, safe
  unsigned int v = (unsigned int)r[i];
  if (v > 1u) atomicOr(flag, 1);
}

// ---------------- helpers ----------------
static __device__ __forceinline__ unsigned rmask16f(const int* resets, int rmode,
                                                    long long tg, int row0) {
  unsigned m = 0;
  if (rmode) {
    const unsigned char* rb = reinterpret_cast<const unsigned char*>(resets);
    uint4 u = *reinterpret_cast<const uint4*>(rb + (size_t)tg * 128 + row0);
    unsigned w0 = u.x, w1 = u.y, w2 = u.z, w3 = u.w;
#pragma unroll
    for (int b = 0; b < 4; ++b) {
      if ((w0 >> (8 * b)) & 0xFFu) m |= 1u << (0 + b);
      if ((w1 >> (8 * b)) & 0xFFu) m |= 1u << (4 + b);
      if ((w2 >> (8 * b)) & 0xFFu) m |= 1u << (8 + b);
      if ((w3 >> (8 * b)) & 0xFFu) m |= 1u << (12 + b);
    }
  } else {
    const uint4* p = reinterpret_cast<const uint4*>(resets + (size_t)tg * 128 + row0);
#pragma unroll
    for (int q = 0; q < 4; ++q) {
      uint4 u = p[q];
      if (u.x) m |= 1u << (q * 4 + 0);
      if (u.y) m |= 1u << (q * 4 + 1);
      if (u.z) m |= 1u << (q * 4 + 2);
      if (u.w) m |= 1u << (q * 4 + 3);
    }
  }
  return m;
}

// r5-proven mirror poll: batched relaxed-agent loads -> ballot (hot-2 then sleep)
static __device__ __forceinline__ void pollTag(const uint32_t* src, unsigned exp,
                                               unsigned short (&v)[16]) {
  for (int it = 0; it < (1 << 13); ++it) {
    uint32_t u[16];
#pragma unroll
    for (int i = 0; i < 16; ++i)
      u[i] = __hip_atomic_load(src + (size_t)i * 512,
                               __ATOMIC_RELAXED, __HIP_MEMORY_SCOPE_AGENT);
    unsigned bad = 0;
#pragma unroll
    for (int i = 0; i < 16; ++i) bad |= ((u[i] >> 16) ^ exp);
    if (__ballot(bad != 0u) == 0ull) {
#pragma unroll
      for (int i = 0; i < 16; ++i) v[i] = (unsigned short)u[i];
      return;
    }
    if (it >= 2) __builtin_amdgcn_s_sleep(1);
  }
#pragma unroll
  for (int i = 0; i < 16; ++i) v[i] = 0;   // bounded watchdog fall-through
}

// lane-0 acquire-poll of gi readiness counter (paired with gemm's release add)
static __device__ __forceinline__ void waitDone(const int* done, int t) {
  if ((threadIdx.x & 63) == 0) {
    for (int it = 0; it < (1 << 16); ++it) {
      if (__hip_atomic_load(done + t, __ATOMIC_ACQUIRE, __HIP_MEMORY_SCOPE_AGENT) >= 12)
        break;
      __builtin_amdgcn_s_sleep(2);
    }
  }
}

// ---------------- GEMM role: gi(t) = x(t)@Wi + bi, tile loop ----------------
// 512 threads, 8 waves of 64x32. Tile = (tt, nn): rows tt*128 (one timestep),
// cols nn*128. gi packed as u32 column-pairs, relaxed agent stores; after the
// tile a release atomicAdd bumps done[tt].
static __device__ void gemm_role(const float* __restrict__ x,
                                 const unsigned short* __restrict__ WiT,
                                 const float* __restrict__ bi,
                                 uint32_t* __restrict__ gw,
                                 int* __restrict__ done,
                                 int tc, int gb, char* smem) {
  unsigned short* Al = reinterpret_cast<unsigned short*>(smem);          // [128][64] swz
  unsigned short* Bl = reinterpret_cast<unsigned short*>(smem + 16384);  // [128][64] swz
  const int tid = threadIdx.x;
  const int lane = tid & 63;
  const int wv = tid >> 6;
  const int wm = wv >> 2, wn = wv & 3;      // 2x4 waves of 64x32
  const int sr = tid >> 2;                  // staging row 0..127
  const int sh = tid & 3;                   // k-quarter (16 elems)
  const int ntiles = 12 * tc;

  for (int tile = gb; tile < ntiles; tile += 128) {
    const int tt = tile / 12, nn = tile % 12;
    const int m0 = tt * 128, n0 = nn * 128;
    const float* xp = x + (size_t)(m0 + sr) * DD + sh * 16;
    const unsigned short* wp = WiT + (size_t)(n0 + sr) * DD + sh * 16;

    float bir[2];
#pragma unroll
    for (int j = 0; j < 2; ++j) bir[j] = bi[n0 + wn * 32 + j * 16 + (lane & 15)];

    f32x4 acc[4][2];
#pragma unroll
    for (int i = 0; i < 4; ++i)
#pragma unroll
      for (int j = 0; j < 2; ++j) acc[i][j] = (f32x4){0.f, 0.f, 0.f, 0.f};

    float4 xa[4];
    uint4 wa[2];
#pragma unroll
    for (int q = 0; q < 4; ++q) xa[q] = *reinterpret_cast<const float4*>(xp + q * 4);
#pragma unroll
    for (int c = 0; c < 2; ++c) wa[c] = *reinterpret_cast<const uint4*>(wp + c * 8);

    for (int kt = 0; kt < 8; ++kt) {
      __syncthreads();
      const int swz = (sr & 7) << 4;
#pragma unroll
      for (int c = 0; c < 2; ++c) {
        const float4 a = xa[2 * c], b = xa[2 * c + 1];
        uint4 u;
        u.x = (uint32_t)f2bf(a.x) | ((uint32_t)f2bf(a.y) << 16);
        u.y = (uint32_t)f2bf(a.z) | ((uint32_t)f2bf(a.w) << 16);
        u.z = (uint32_t)f2bf(b.x) | ((uint32_t)f2bf(b.y) << 16);
        u.w = (uint32_t)f2bf(b.z) | ((uint32_t)f2bf(b.w) << 16);
        const int off = sr * 128 + ((sh * 32 + c * 16) ^ swz);
        *reinterpret_cast<uint4*>(reinterpret_cast<char*>(Al) + off) = u;
      }
#pragma unroll
      for (int c = 0; c < 2; ++c) {
        const int off = sr * 128 + ((sh * 32 + c * 16) ^ swz);
        *reinterpret_cast<uint4*>(reinterpret_cast<char*>(Bl) + off) = wa[c];
      }
      if (kt < 7) {
#pragma unroll
        for (int q = 0; q < 4; ++q)
          xa[q] = *reinterpret_cast<const float4*>(xp + (kt + 1) * 64 + q * 4);
#pragma unroll
        for (int c = 0; c < 2; ++c)
          wa[c] = *reinterpret_cast<const uint4*>(wp + (kt + 1) * 64 + c * 8);
      }
      __syncthreads();
#pragma unroll
      for (int kk = 0; kk < 2; ++kk) {
        s16x8 af[4], bfr[2];
        const int kb = kk * 64 + ((lane >> 4) << 4);
        const int sw = (lane & 7) << 4;
#pragma unroll
        for (int i = 0; i < 4; ++i) {
          const int row = wm * 64 + i * 16 + (lane & 15);
          af[i] = ldsfrag(reinterpret_cast<const char*>(Al) + row * 128 + (kb ^ sw));
        }
#pragma unroll
        for (int j = 0; j < 2; ++j) {
          const int row = wn * 32 + j * 16 + (lane & 15);
          bfr[j] = ldsfrag(reinterpret_cast<const char*>(Bl) + row * 128 + (kb ^ sw));
        }
#pragma unroll
        for (int i = 0; i < 4; ++i)
#pragma unroll
          for (int j = 0; j < 2; ++j)
            acc[i][j] = __builtin_amdgcn_mfma_f32_16x16x32_bf16(af[i], bfr[j], acc[i][j], 0, 0, 0);
      }
    }
    // epilogue: pack column pairs, relaxed agent u32 stores
#pragma unroll
    for (int i = 0; i < 4; ++i) {
      const int row0 = m0 + wm * 64 + i * 16 + ((lane >> 4) << 2);
#pragma unroll
      for (int j = 0; j < 2; ++j) {
        const int col = n0 + wn * 32 + j * 16 + (lane & 15);
#pragma unroll
        for (int r = 0; r < 4; ++r) {
          float s = acc[i][j][r] + bir[j];
          unsigned myb = f2bf(s);
          unsigned hib = (unsigned)__shfl_down((int)myb, 1) & 0xFFFFu;
          if (!(lane & 1)) {
            uint32_t word = myb | (hib << 16);
            __hip_atomic_store(gw + (size_t)(row0 + r) * 768 + (col >> 1), word,
                               __ATOMIC_RELAXED, __HIP_MEMORY_SCOPE_AGENT);
          }
        }
      }
    }
    __syncthreads();  // all stores drained (vmcnt0 per wave) before publish
    if (tid == 0)
      __hip_atomic_fetch_add(done + tt, 1, __ATOMIC_RELEASE, __HIP_MEMORY_SCOPE_AGENT);
  }
}

// ---------------- RNN role: r5-proven persistent recurrent core ----------------
static __device__ void rnn_role(const uint32_t* __restrict__ gw,
                                const unsigned short* __restrict__ Wpk,
                                const float* __restrict__ bhn,
                                const int* __restrict__ resets,
                                uint32_t* hxt, float* hbF,
                                int rmode, const int* __restrict__ done,
                                float* __restrict__ ys,
                                int t0, int tc, char* smem) {
  char* Hlb = smem;                                        // 16384 B
  float* ax = reinterpret_cast<float*>(smem + 16384);      // 26112 B

  const int tid = threadIdx.x;
  const int lane = tid & 63;
  const int wv = tid >> 6;
  const int w = wv & 1, ks = wv >> 1;
  const int cj = blockIdx.x >> 3, rg = blockIdx.x & 7;
  const int ec = tid & 31, eb = tid >> 5;
  const int bglob = rg * 16 + eb;
  const int colglob = cj * 32 + ec;
  const int gsh = (colglob & 1) << 4;   // gi word half

  // Wh fragments -> registers (once)
  uint4 wreg[3][4];
  {
    const unsigned short* wbase = Wpk + (size_t)cj * 96 * 512
                                + (size_t)(w * 16 + (lane & 15)) * 512
                                + ks * 128 + (lane >> 4) * 8;
#pragma unroll
    for (int g = 0; g < 3; ++g)
#pragma unroll
      for (int kk = 0; kk < 4; ++kk)
        wreg[g][kk] = *reinterpret_cast<const uint4*>(wbase + g * 32 * 512 + kk * 32);
  }

  const float bhn_c = bhn[colglob];
  float h_old = hbF[(size_t)bglob * 512 + colglob];   // f32 carry at chunk start

  unsigned short v[16];
  pollTag(hxt + (size_t)(t0 & 1) * 65536 + (size_t)rg * 8192 + tid, (unsigned)t0 & 0xFFFFu, v);

  unsigned mask = rmask16f(resets, rmode, t0, rg * 16);
  uint32_t gir, giz, gin;
  {
    waitDone(done, 0);
    const uint32_t* gp = gw + (size_t)bglob * 768 + (colglob >> 1);
    uint32_t wr = __hip_atomic_load(gp, __ATOMIC_RELAXED, __HIP_MEMORY_SCOPE_AGENT);
    uint32_t wz = __hip_atomic_load(gp + 256, __ATOMIC_RELAXED, __HIP_MEMORY_SCOPE_AGENT);
    uint32_t wn_ = __hip_atomic_load(gp + 512, __ATOMIC_RELAXED, __HIP_MEMORY_SCOPE_AGENT);
    gir = (wr >> gsh) & 0xFFFFu; giz = (wz >> gsh) & 0xFFFFu; gin = (wn_ >> gsh) & 0xFFFFu;
  }

  int soff[16];
#pragma unroll
  for (int i = 0; i < 16; ++i)
    soff[i] = i * 1024 + (((((tid * 2) >> 4) ^ (i & 7)) << 4) | ((tid & 7) * 2));

  for (int t = 0; t < tc; ++t) {
    const long long tg = t0 + t;
    // stage Hl (thread owns column tid), reset-masked
#pragma unroll
    for (int i = 0; i < 16; ++i) {
      unsigned short x = ((mask >> i) & 1u) ? (unsigned short)0 : v[i];
      *reinterpret_cast<unsigned short*>(Hlb + soff[i]) = x;
    }
    __syncthreads();  // B1
    // MFMA: W from VGPR, H from LDS
    f32x4 acc[3];
#pragma unroll
    for (int g = 0; g < 3; ++g) acc[g] = (f32x4){0.f, 0.f, 0.f, 0.f};
    {
      const int rowb = lane & 15;
      const char* hrow = Hlb + rowb * 1024;
      const int hsw = (rowb & 7) << 4;
      const int kplusB = (lane >> 4) << 4;
      s16x8 hfrag[4];
#pragma unroll
      for (int kk = 0; kk < 4; ++kk) {
        const int kbB = (ks * 128 + kk * 32) * 2 + kplusB;
        hfrag[kk] = ldsfrag(hrow + (kbB ^ hsw));
      }
#pragma unroll
      for (int g = 0; g < 3; ++g)
#pragma unroll
        for (int kk = 0; kk < 4; ++kk)
          acc[g] = __builtin_amdgcn_mfma_f32_16x16x32_bf16(
              __builtin_bit_cast(s16x8, wreg[g][kk]), hfrag[kk], acc[g], 0, 0, 0);
    }
    {  // partials -> LDS (padded stride 17)
      const int mh = (lane >> 4) << 2, nnn = lane & 15;
#pragma unroll
      for (int g = 0; g < 3; ++g) {
        float* dst = ax + ((ks * 2 + w) * 3 + g) * 272 + nnn;
#pragma unroll
        for (int r = 0; r < 4; ++r) dst[(mh + r) * 17] = acc[g][r];
      }
    }
    __syncthreads();  // B2
    // elementwise GRU update
    {
      const int wc = ec >> 4, mc = ec & 15;
      float s0a = 0.f, s1a = 0.f, s2a = 0.f;
#pragma unroll
      for (int k2 = 0; k2 < 4; ++k2) {
        const float* p = ax + ((k2 * 2 + wc) * 3) * 272 + mc * 17 + eb;
        s0a += p[0]; s1a += p[272]; s2a += p[544];
      }
      const float r = 1.f / (1.f + __expf(-(b2f(gir) + s0a)));
      const float z = 1.f / (1.f + __expf(-(b2f(giz) + s1a)));
      const float hu = ((mask >> eb) & 1u) ? 0.f : h_old;
      const float pre = b2f(gin) + r * (s2a + bhn_c);
      const float n = 1.f - 2.f / (1.f + __expf(2.f * pre));
      float hn = (1.f - z) * n + z * hu;
      hn = fminf(1.f, fmaxf(-1.f, hn));
      __builtin_nontemporal_store(hn, ys + ((size_t)tg * 128 + bglob) * 512 + colglob);
      const uint32_t tagged = (((uint32_t)(tg + 1) & 0xFFFFu) << 16) | (uint32_t)f2bf(hn);
      __hip_atomic_store(hxt + (size_t)((tg + 1) & 1) * 65536 + (size_t)bglob * 512 + colglob,
                         tagged, __ATOMIC_RELAXED, __HIP_MEMORY_SCOPE_AGENT);
      if (t == tc - 1) hbF[(size_t)bglob * 512 + colglob] = hn;
      h_old = hn;
    }
    if (t + 1 < tc) {
      // gi(t+1): readiness check + agent word loads (hidden under h poll)
      waitDone(done, t + 1);
      const uint32_t* gp = gw + ((size_t)(t + 1) * 128 + bglob) * 768 + (colglob >> 1);
      uint32_t wr = __hip_atomic_load(gp, __ATOMIC_RELAXED, __HIP_MEMORY_SCOPE_AGENT);
      uint32_t wz = __hip_atomic_load(gp + 256, __ATOMIC_RELAXED, __HIP_MEMORY_SCOPE_AGENT);
      uint32_t wn_ = __hip_atomic_load(gp + 512, __ATOMIC_RELAXED, __HIP_MEMORY_SCOPE_AGENT);
      unsigned nmask = rmask16f(resets, rmode, tg + 1, rg * 16);
      // h(t+1) poll (r5 protocol)
      pollTag(hxt + (size_t)((tg + 1) & 1) * 65536 + (size_t)rg * 8192 + tid,
              (unsigned)(tg + 1) & 0xFFFFu, v);
      gir = (wr >> gsh) & 0xFFFFu; giz = (wz >> gsh) & 0xFFFFu; gin = (wn_ >> gsh) & 0xFFFFu;
      mask = nmask;
    }
  }
}

// ---------------- fused kernel ----------------
__global__ __launch_bounds__(512) void fused(const float* __restrict__ x,
                                             const unsigned short* __restrict__ WiT,
                                             const float* __restrict__ bi,
                                             uint32_t* gw,
                                             const unsigned short* __restrict__ Wpk,
                                             const float* __restrict__ bhn,
                                             const int* __restrict__ resets,
                                             uint32_t* hxt, float* hbF,
                                             const int* __restrict__ rmodep,
                                             int* done,
                                             float* __restrict__ ys,
                                             int t0, int tc) {
  __shared__ char smem[SM_BYTES];
  if (blockIdx.x >= 128) {
    gemm_role(x, WiT, bi, gw, done, tc, blockIdx.x - 128, smem);
    return;
  }
  rnn_role(gw, Wpk, bhn, resets, hxt, hbF, *rmodep, done, ys, t0, tc, smem);
}

// ---------------- launch ----------------
extern "C" void kernel_launch(void* const* d_in, const int* in_sizes, int n_in,
                              void* d_out, int out_size, void* d_ws, size_t ws_size,
                              hipStream_t stream) {
  const float* h0 = (const float*)d_in[0];
  const float* ins = (const float*)d_in[1];
  const int* rst = (const int*)d_in[2];
  const float* Wi = (const float*)d_in[3];
  const float* bi = (const float*)d_in[4];
  const float* Whrz = (const float*)d_in[5];
  const float* Whn = (const float*)d_in[6];
  const float* bhn = (const float*)d_in[7];
  float* ys = (float*)d_out;

  char* ws = (char*)d_ws;
  unsigned short* WiT = (unsigned short*)(ws);              // 1,572,864 B
  unsigned short* Wpk = (unsigned short*)(ws + 1572864);    // 1,572,864 B
  uint32_t* hxt = (uint32_t*)(ws + 3145728);                //   524,288 B
  float* hbF = (float*)(ws + 3670016);                      //   262,144 B
  int* flag = (int*)(ws + 3932160);                         //         4 B (rmode)
  int* done = (int*)(ws + 3936256);                         //     4,096 B
  const size_t gi_off = 3940352;
  uint32_t* gw = (uint32_t*)(ws + gi_off);

  size_t avail = (ws_size > gi_off) ? (ws_size - gi_off) : 0;
  long long tcap = (long long)(avail / (128ull * 1536ull * 2ull));
  int Tc = (int)((tcap > 1024) ? 1024 : tcap);
  Tc &= ~1;
  if (Tc < 2) Tc = 2;

  hipMemsetAsync(flag, 0, 4, stream);                                  // rmode
  hipMemsetAsync(hxt, 0, 524288, stream);        // both slots -> tag 0 (replay-safe)
  tag0<<<dim3(128), dim3(512), 0, stream>>>(h0, hxt, hbF);             // slot0 = h(0)
  prep<<<dim3(6144), dim3(256), 0, stream>>>(Wi, Whrz, Whn, WiT, Wpk);
  scanR<<<dim3(128), dim3(256), 0, stream>>>(rst, flag);

  for (int t0 = 0; t0 < 1024; t0 += Tc) {
    int tc = 1024 - t0;
    if (tc > Tc) tc = Tc;
    hipMemsetAsync(done, 0, (size_t)tc * 4, stream);
    fused<<<dim3(256), dim3(512), 0, stream>>>(ins + (size_t)t0 * 65536, WiT, bi, gw,
                                               Wpk, bhn, rst, hxt, hbF, flag, done, ys,
                                               t0, tc);
  }
}

// Round 8
// 3515.896 us; speedup vs baseline: 2.7807x; 2.7807x over previous
//
#include <hip/hip_runtime.h>
#include <stdint.h>

// ScannedRNN: T=1024, B=128, D=512 GRU with resets + straight-through clip.
// prep (weight convert/pack) -> rnnB (persistent 128-block recurrent kernel;
// Wh AND Wi slices in VGPRs; x@Wi folded into the step (no gi buffer, no
// gemmA); h exchanged as tagged bf16 words (epoch<<16|bf16), 2-slot parity,
// relaxed agent scope (r5-proven); per-producer retry-masked batched poll).

typedef float f32x4 __attribute__((ext_vector_type(4)));
typedef short s16x8 __attribute__((ext_vector_type(8)));

#define DD 512
#define BB 128
#define TT 1024

static __device__ __forceinline__ unsigned short f2bf(float f) {
  uint32_t u = __builtin_bit_cast(uint32_t, f);
  u = (u + 0x7fffu + ((u >> 16) & 1u)) >> 16;   // RNE
  return (unsigned short)u;
}
static __device__ __forceinline__ float b2f(uint32_t bits) {
  return __builtin_bit_cast(float, bits << 16);
}
static __device__ __forceinline__ s16x8 ldsfrag(const char* p) {
  return __builtin_bit_cast(s16x8, *reinterpret_cast<const uint4*>(p));
}

// ---------------- prep: pack Wi and Wh slices, bf16, per-column-block ----------------
// Wipk/Wpk [cj][c96][k]: c96 = gate*32+cc; gate 0=r,1=z,2=n; k = 0..511.
__global__ void prep(const float* __restrict__ Wi, const float* __restrict__ Whrz,
                     const float* __restrict__ Whn,
                     unsigned short* __restrict__ Wipk, unsigned short* __restrict__ Wpk) {
  int i = blockIdx.x * 256 + threadIdx.x;
  if (i < 786432) {
    int ck = i >> 9, k = i & 511;
    int cj = ck / 96, c96 = ck % 96;
    int g = c96 >> 5, cc = c96 & 31;
    Wipk[i] = f2bf(Wi[(size_t)k * 1536 + g * 512 + cj * 32 + cc]);
  } else {
    int j = i - 786432;
    int ck = j >> 9, k = j & 511;
    int cj = ck / 96, c96 = ck % 96;
    int g = c96 >> 5, cc = c96 & 31;
    float v = (g < 2) ? Whrz[(size_t)k * 1024 + g * 512 + cj * 32 + cc]
                      : Whn[(size_t)k * 512 + cj * 32 + cc];
    Wpk[j] = f2bf(v);
  }
}

// ---------------- tag0: slot0 <- tagged(epoch 0) h0; f32 carry <- h0 ----------
__global__ void tag0(const float* __restrict__ h0, uint32_t* __restrict__ hxt,
                     float* __restrict__ hbF) {
  int i = blockIdx.x * 512 + threadIdx.x;   // 65536
  float v = h0[i];
  hxt[i] = (uint32_t)f2bf(v);               // tag 0
  hbF[i] = v;
}

// ---------------- resets dtype probe (bool bytes vs int32) ----------------
__global__ void scanR(const int* __restrict__ r, int* __restrict__ flag) {
  int i = blockIdx.x * 256 + threadIdx.x;       // 32768 ints = 131072 bytes, safe
  unsigned int v = (unsigned int)r[i];
  if (v > 1u) atomicOr(flag, 1);
}

// ---------------- helpers ----------------
static __device__ __forceinline__ unsigned rmask16f(const int* resets, int rmode,
                                                    long long tg, int row0) {
  unsigned m = 0;
  if (rmode) {
    const unsigned char* rb = reinterpret_cast<const unsigned char*>(resets);
    uint4 u = *reinterpret_cast<const uint4*>(rb + (size_t)tg * 128 + row0);
    unsigned w0 = u.x, w1 = u.y, w2 = u.z, w3 = u.w;
#pragma unroll
    for (int b = 0; b < 4; ++b) {
      if ((w0 >> (8 * b)) & 0xFFu) m |= 1u << (0 + b);
      if ((w1 >> (8 * b)) & 0xFFu) m |= 1u << (4 + b);
      if ((w2 >> (8 * b)) & 0xFFu) m |= 1u << (8 + b);
      if ((w3 >> (8 * b)) & 0xFFu) m |= 1u << (12 + b);
    }
  } else {
    const uint4* p = reinterpret_cast<const uint4*>(resets + (size_t)tg * 128 + row0);
#pragma unroll
    for (int q = 0; q < 4; ++q) {
      uint4 u = p[q];
      if (u.x) m |= 1u << (q * 4 + 0);
      if (u.y) m |= 1u << (q * 4 + 1);
      if (u.z) m |= 1u << (q * 4 + 2);
      if (u.w) m |= 1u << (q * 4 + 3);
    }
  }
  return m;
}

// batched tag poll with per-producer retry masking: a thread's 16 words all
// come from ONE producer (the block owning column tid), so once fresh they
// stay captured; exec-masked lanes issue no further loads.
static __device__ __forceinline__ void pollTag(const uint32_t* src, unsigned exp,
                                               unsigned short (&v)[16]) {
  bool need = true;
  for (int it = 0; it < (1 << 12); ++it) {
    if (need) {
      uint32_t u[16];
#pragma unroll
      for (int i = 0; i < 16; ++i)
        u[i] = __hip_atomic_load(src + (size_t)i * 512,
                                 __ATOMIC_RELAXED, __HIP_MEMORY_SCOPE_AGENT);
      unsigned bad = 0;
#pragma unroll
      for (int i = 0; i < 16; ++i) bad |= ((u[i] >> 16) ^ exp);
      if (bad == 0u) {
#pragma unroll
        for (int i = 0; i < 16; ++i) v[i] = (unsigned short)u[i];
        need = false;
      }
    }
    if (__ballot(need ? 1 : 0) == 0ull) break;
    if (it >= 1) __builtin_amdgcn_s_sleep(1);
  }
}

// ---------------- rnnB: persistent recurrent kernel, x@Wi folded in ----------------
// 128 blocks = 16 col-blocks (cj) x 8 row groups (rg). Per step:
//   prefetch x(t+1) f32 -> stage X(t),H(t) bf16 in LDS -> 24 MFMA/wave
//   (Wi x X into r,z,nx; Wh x H into r,z,nh; weights in VGPRs) -> ax reduce
//   -> elementwise GRU -> publish tagged h(t+1) -> poll peers' h(t+1).
#define RNN_SMEM (16384 + 16384 + 34816)   // Hlb + Xlb + ax[8][4][272]f32

__global__ __launch_bounds__(512) void rnnB(const float* __restrict__ x,
                                            const unsigned short* __restrict__ Wipk,
                                            const unsigned short* __restrict__ Wpk,
                                            const float* __restrict__ bi,
                                            const float* __restrict__ bhn,
                                            const int* __restrict__ resets,
                                            uint32_t* hxt,                 // [2][128][512]
                                            const float* __restrict__ hbF, // [128][512]
                                            const int* __restrict__ rmodep,
                                            float* __restrict__ ys,
                                            int tc) {
  extern __shared__ char smem[];
  char* Hlb = smem;                                       // 16384 B
  char* Xlb = smem + 16384;                               // 16384 B
  float* ax = reinterpret_cast<float*>(smem + 32768);     // 34816 B

  const int tid = threadIdx.x;
  const int lane = tid & 63;
  const int wv = tid >> 6;
  const int w = wv & 1, ks = wv >> 1;
  const int cj = blockIdx.x >> 3, rg = blockIdx.x & 7;
  const int ec = tid & 31, eb = tid >> 5;          // elementwise: col-in-32, row-in-16
  const int bglob = rg * 16 + eb;
  const int colglob = cj * 32 + ec;
  const int rmode = *rmodep;

  // ---- Wh + Wi fragments -> registers (once per launch) ----
  uint4 wreg[3][4], wireg[3][4];
  {
    const size_t fb = (size_t)cj * 96 * 512
                    + (size_t)(w * 16 + (lane & 15)) * 512
                    + ks * 128 + (lane >> 4) * 8;
#pragma unroll
    for (int g = 0; g < 3; ++g)
#pragma unroll
      for (int kk = 0; kk < 4; ++kk) {
        wreg[g][kk]  = *reinterpret_cast<const uint4*>(Wpk  + fb + g * 32 * 512 + kk * 32);
        wireg[g][kk] = *reinterpret_cast<const uint4*>(Wipk + fb + g * 32 * 512 + kk * 32);
      }
  }

  const float bhn_c = bhn[colglob];
  float bir3[3];
#pragma unroll
  for (int g = 0; g < 3; ++g) bir3[g] = bi[g * 512 + colglob];
  float h_old = hbF[(size_t)bglob * 512 + colglob];

  // initial h(0) panel from slot 0 (tag 0, written by tag0)
  unsigned short v[16];
  pollTag(hxt + (size_t)rg * 8192 + tid, 0u, v);
  unsigned mask = rmask16f(resets, rmode, 0, rg * 16);

  // x(0) prefetch: thread owns k-column tid, 16 batch rows
  float xa[16];
#pragma unroll
  for (int i = 0; i < 16; ++i)
    xa[i] = x[(size_t)(rg * 16 + i) * 512 + tid];

  int soff[16];
#pragma unroll
  for (int i = 0; i < 16; ++i)
    soff[i] = i * 1024 + (((((tid * 2) >> 4) ^ (i & 7)) << 4) | ((tid & 7) * 2));

  for (int t = 0; t < tc; ++t) {
    // ---- issue x(t+1) loads now; they complete during this step's compute ----
    float xaN[16];
    const bool haveN = (t + 1 < tc);
    if (haveN) {
#pragma unroll
      for (int i = 0; i < 16; ++i)
        xaN[i] = x[((size_t)(t + 1) * 128 + rg * 16 + i) * 512 + tid];
    }
    // ---- stage H(t) (reset-masked) and X(t) (f32->bf16) ----
#pragma unroll
    for (int i = 0; i < 16; ++i) {
      unsigned short hv = ((mask >> i) & 1u) ? (unsigned short)0 : v[i];
      *reinterpret_cast<unsigned short*>(Hlb + soff[i]) = hv;
      *reinterpret_cast<unsigned short*>(Xlb + soff[i]) = f2bf(xa[i]);
    }
    __syncthreads();  // B1
    // ---- MFMA: 24 per wave; weights from VGPR, X/H frags from LDS ----
    f32x4 accR = (f32x4){0.f, 0.f, 0.f, 0.f};
    f32x4 accZ = accR, accNX = accR, accNH = accR;
    {
      const int rowb = lane & 15;
      const int hsw = (rowb & 7) << 4;
      const int kplusB = (lane >> 4) << 4;
      s16x8 hfrag[4], xfrag[4];
#pragma unroll
      for (int kk = 0; kk < 4; ++kk) {
        const int kbB = (ks * 128 + kk * 32) * 2 + kplusB;
        hfrag[kk] = ldsfrag(Hlb + rowb * 1024 + (kbB ^ hsw));
        xfrag[kk] = ldsfrag(Xlb + rowb * 1024 + (kbB ^ hsw));
      }
#pragma unroll
      for (int kk = 0; kk < 4; ++kk) {
        accR = __builtin_amdgcn_mfma_f32_16x16x32_bf16(
            __builtin_bit_cast(s16x8, wireg[0][kk]), xfrag[kk], accR, 0, 0, 0);
        accZ = __builtin_amdgcn_mfma_f32_16x16x32_bf16(
            __builtin_bit_cast(s16x8, wireg[1][kk]), xfrag[kk], accZ, 0, 0, 0);
        accNX = __builtin_amdgcn_mfma_f32_16x16x32_bf16(
            __builtin_bit_cast(s16x8, wireg[2][kk]), xfrag[kk], accNX, 0, 0, 0);
        accR = __builtin_amdgcn_mfma_f32_16x16x32_bf16(
            __builtin_bit_cast(s16x8, wreg[0][kk]), hfrag[kk], accR, 0, 0, 0);
        accZ = __builtin_amdgcn_mfma_f32_16x16x32_bf16(
            __builtin_bit_cast(s16x8, wreg[1][kk]), hfrag[kk], accZ, 0, 0, 0);
        accNH = __builtin_amdgcn_mfma_f32_16x16x32_bf16(
            __builtin_bit_cast(s16x8, wreg[2][kk]), hfrag[kk], accNH, 0, 0, 0);
      }
    }
    {  // partials -> LDS: 4 planes (r, z, nx, nh), padded stride 17
      const int mh = (lane >> 4) << 2, nn = lane & 15;
      float* base = ax + (size_t)((ks * 2 + w) * 4) * 272 + nn;
#pragma unroll
      for (int r = 0; r < 4; ++r) {
        base[(mh + r) * 17] = accR[r];
        base[272 + (mh + r) * 17] = accZ[r];
        base[544 + (mh + r) * 17] = accNX[r];
        base[816 + (mh + r) * 17] = accNH[r];
      }
    }
    __syncthreads();  // B2
    // ---- elementwise GRU update: one (row eb, col ec) per thread ----
    {
      const int wc = ec >> 4, mc = ec & 15;
      float s0 = 0.f, s1 = 0.f, s2x = 0.f, s2h = 0.f;
#pragma unroll
      for (int k2 = 0; k2 < 4; ++k2) {
        const float* p = ax + (size_t)((k2 * 2 + wc) * 4) * 272 + mc * 17 + eb;
        s0 += p[0]; s1 += p[272]; s2x += p[544]; s2h += p[816];
      }
      const float r = 1.f / (1.f + __expf(-(bir3[0] + s0)));
      const float z = 1.f / (1.f + __expf(-(bir3[1] + s1)));
      const float hu = ((mask >> eb) & 1u) ? 0.f : h_old;
      const float pre = (bir3[2] + s2x) + r * (s2h + bhn_c);
      const float n = 1.f - 2.f / (1.f + __expf(2.f * pre));
      float hn = (1.f - z) * n + z * hu;
      hn = fminf(1.f, fmaxf(-1.f, hn));
      // publish FIRST (critical path), then output store
      const uint32_t tagged = (((uint32_t)(t + 1) & 0xFFFFu) << 16) | (uint32_t)f2bf(hn);
      __hip_atomic_store(hxt + (size_t)((t + 1) & 1) * 65536 + (size_t)bglob * 512 + colglob,
                         tagged, __ATOMIC_RELAXED, __HIP_MEMORY_SCOPE_AGENT);
      __builtin_nontemporal_store(hn, ys + ((size_t)t * 128 + bglob) * 512 + colglob);
      h_old = hn;
    }
    if (haveN) {
      unsigned nmask = rmask16f(resets, rmode, t + 1, rg * 16);
      pollTag(hxt + (size_t)((t + 1) & 1) * 65536 + (size_t)rg * 8192 + tid,
              (unsigned)(t + 1) & 0xFFFFu, v);
      mask = nmask;
#pragma unroll
      for (int i = 0; i < 16; ++i) xa[i] = xaN[i];
    }
  }
}

// ---------------- launch ----------------
extern "C" void kernel_launch(void* const* d_in, const int* in_sizes, int n_in,
                              void* d_out, int out_size, void* d_ws, size_t ws_size,
                              hipStream_t stream) {
  const float* h0 = (const float*)d_in[0];
  const float* ins = (const float*)d_in[1];
  const int* rst = (const int*)d_in[2];
  const float* Wi = (const float*)d_in[3];
  const float* bi = (const float*)d_in[4];
  const float* Whrz = (const float*)d_in[5];
  const float* Whn = (const float*)d_in[6];
  const float* bhn = (const float*)d_in[7];
  float* ys = (float*)d_out;

  char* ws = (char*)d_ws;
  unsigned short* Wpk = (unsigned short*)(ws);              // 1,572,864 B
  unsigned short* Wipk = (unsigned short*)(ws + 1572864);   // 1,572,864 B
  uint32_t* hxt = (uint32_t*)(ws + 3145728);                //   524,288 B ([2][128][512])
  float* hbF = (float*)(ws + 3670016);                      //   262,144 B
  int* flag = (int*)(ws + 3932160);                         //         4 B (rmode)

  hipMemsetAsync(flag, 0, 4, stream);                                  // rmode
  hipMemsetAsync(hxt, 0, 524288, stream);        // both slots -> tag 0 (replay-safe)
  tag0<<<dim3(128), dim3(512), 0, stream>>>(h0, hxt, hbF);             // slot0 = h(0)
  prep<<<dim3(6144), dim3(256), 0, stream>>>(Wi, Whrz, Whn, Wipk, Wpk);
  scanR<<<dim3(128), dim3(256), 0, stream>>>(rst, flag);
  hipFuncSetAttribute((const void*)rnnB, hipFuncAttributeMaxDynamicSharedMemorySize,
                      RNN_SMEM);
  rnnB<<<dim3(128), dim3(512), RNN_SMEM, stream>>>(ins, Wipk, Wpk, bi, bhn, rst,
                                                   hxt, hbF, flag, ys, 1024);
}